// Round 5
// baseline (345.955 us; speedup 1.0000x reference)
//
#include <hip/hip_runtime.h>
#include <hip/hip_bf16.h>
#include <stdint.h>

// Problem: B=8192, D=1024, U=1024.
// z = [x|h] @ Wcat + b, Wcat[k, n] with n = u*4 + g (gate-interleaved), k in [0,2048)
// GEMM: M=8192, N=4096, K=2048, bf16 inputs, fp32 accum, fused LSTM epilogue.
// R5: inner op 16x16x32 -> 32x32x16 (2495 vs 2176 TF ubench; half the MFMA instrs).

#define MM 8192
#define KK 2048
#define NN 4096
#define BM 128
#define BN 128
#define BK 64

typedef __attribute__((ext_vector_type(8))) __bf16 bf16x8;
typedef __attribute__((ext_vector_type(4))) float floatx4;
typedef __attribute__((ext_vector_type(16))) float floatx16;
typedef __attribute__((ext_vector_type(8))) unsigned short ushort8_t;

__device__ __forceinline__ unsigned short f2bf(float f) {
    unsigned int u = __float_as_uint(f);
    u += 0x7FFF + ((u >> 16) & 1);   // RNE; inputs are finite
    return (unsigned short)(u >> 16);
}

__device__ __forceinline__ float fast_sigmoid(float x) {
    return 1.0f / (1.0f + __expf(-x));
}

// tanh(x) = 2*sigmoid(2x)-1; exp->inf saturates correctly to -1/+1
__device__ __forceinline__ float fast_tanh(float x) {
    return 2.0f / (1.0f + __expf(-2.0f * x)) - 1.0f;
}

__device__ __forceinline__ void async_copy16(const void* g, void* l) {
    __builtin_amdgcn_global_load_lds(
        (const __attribute__((address_space(1))) void*)g,
        (__attribute__((address_space(3))) void*)l,
        16, 0, 0);
}

// ---------------- fused pack kernel ----------------
// blocks [0,2048): transpose weights -> bf16 Wt[4096][2048], row n=u*4+g
// blocks [2048,10240): pack x|h -> bf16 A[8192][2048], 8 elem/thread
__global__ void pack_all(const float* __restrict__ x, const float* __restrict__ h,
                         const float* __restrict__ Wi, const float* __restrict__ Wf,
                         const float* __restrict__ Wc, const float* __restrict__ Wo,
                         const float* __restrict__ Ui, const float* __restrict__ Uf,
                         const float* __restrict__ Uc, const float* __restrict__ Uo,
                         unsigned short* __restrict__ A,
                         unsigned short* __restrict__ Wt) {
    __shared__ float tile[64][65];
    int blk = blockIdx.x;
    int tid = threadIdx.x;
    if (blk >= 2048) {
        // ---- A pack ----
        int t = (blk - 2048) * 256 + tid;
        long base = (long)t * 8;
        int row = (int)(base >> 11);
        int col = (int)(base & 2047);
        const float* src = (col < 1024) ? (x + (long)row * 1024 + col)
                                        : (h + (long)row * 1024 + (col - 1024));
        float4 v0 = *(const float4*)src;
        float4 v1 = *(const float4*)(src + 4);
        ushort8_t o;
        o[0] = f2bf(v0.x); o[1] = f2bf(v0.y); o[2] = f2bf(v0.z); o[3] = f2bf(v0.w);
        o[4] = f2bf(v1.x); o[5] = f2bf(v1.y); o[6] = f2bf(v1.z); o[7] = f2bf(v1.w);
        *(ushort8_t*)(A + base) = o;
        return;
    }
    // ---- W transpose ----
    int z = blk >> 8;                            // 0..7: Wi..Wo, Ui..Uo
    int rem = blk & 255;
    const float* src;
    switch (z) {
        case 0: src = Wi; break; case 1: src = Wf; break;
        case 2: src = Wc; break; case 3: src = Wo; break;
        case 4: src = Ui; break; case 5: src = Uf; break;
        case 6: src = Uc; break; default: src = Uo; break;
    }
    int g = z & 3;
    int koff = (z >= 4) ? 1024 : 0;
    int d0 = (rem >> 4) * 64;
    int u0 = (rem & 15) * 64;

    int j = tid & 63;
    int ib = tid >> 6;                            // 0..3
#pragma unroll
    for (int p = 0; p < 16; ++p) {
        int i = p * 4 + ib;
        tile[i][j] = src[(long)(d0 + i) * 1024 + u0 + j];
    }
    __syncthreads();
    int i2 = (tid & 31) * 2;
    int jb = tid >> 5;                            // 0..7
#pragma unroll
    for (int p = 0; p < 8; ++p) {
        int j2 = p * 8 + jb;
        unsigned short a = f2bf(tile[i2][j2]);
        unsigned short b = f2bf(tile[i2 + 1][j2]);
        long orow = (long)((u0 + j2) * 4 + g);
        *(ushort2*)(Wt + orow * 2048 + koff + d0 + i2) = make_ushort2(a, b);
    }
}

// ---------------- fused GEMM + LSTM epilogue ----------------
// grid 2048 linear, bx = id & 63 (M tile, fast), by = id >> 6 (N tile).
// LDS (BK=64): As[128][64] bf16 (16KB) + Bs[128][64] (16KB), XOR-swizzled:
//   chunk slot c' = c ^ (row & 7), chunk = 16B (8 bf16), row stride = 128B.
// Inner op: v_mfma_f32_32x32x16_bf16; wave tile 64x64 = 2x2 of 32x32.
// Epilogue zs overlaps staging LDS: 64 x 132 fp32 (33792 B).
__global__ __launch_bounds__(256) void lstm_gemm(
    const unsigned short* __restrict__ A,    // [8192][2048] bf16
    const unsigned short* __restrict__ Wt,   // [4096][2048] bf16 (row n = u*4+g)
    const float* __restrict__ c_in,
    const float* __restrict__ Vi, const float* __restrict__ Vf, const float* __restrict__ Vo,
    const float* __restrict__ bi_p, const float* __restrict__ bf_p,
    const float* __restrict__ bc_p, const float* __restrict__ bo_p,
    float* __restrict__ out) {
    __shared__ __align__(16) char smem[33792];
    unsigned short* As = (unsigned short*)smem;
    unsigned short* Bs = (unsigned short*)(smem + 16384);

    int tid = threadIdx.x;
    int wave = tid >> 6;
    int lane = tid & 63;
    int wm = wave >> 1, wn = wave & 1;

    int id = blockIdx.x;
    int bx = id & 63;                             // M tile (fast)
    int by = id >> 6;                             // N tile
    int rm0 = bx * BM;
    int cn0 = by * BN;

    // staging: per wave 4 chunks of 1KB each for A and B (8 rows x 128B per chunk)
    // swizzle: lane (r_l = lane>>3, s = lane&7) fetches global chunk c = s ^ r_l
    int r_l = lane >> 3;
    int kc = ((lane & 7) ^ r_l) * 8;
    int voff = (wave * 32 + r_l) * 2048 + kc;
    // 8 loop-invariant per-lane base pointers (VGPR pairs, set once)
    const unsigned short* aP0 = A + (long)rm0 * 2048 + voff;
    const unsigned short* aP1 = aP0 + 8 * 2048;
    const unsigned short* aP2 = aP0 + 16 * 2048;
    const unsigned short* aP3 = aP0 + 24 * 2048;
    const unsigned short* bP0 = Wt + (long)cn0 * 2048 + voff;
    const unsigned short* bP1 = bP0 + 8 * 2048;
    const unsigned short* bP2 = bP0 + 16 * 2048;
    const unsigned short* bP3 = bP0 + 24 * 2048;
    char* ldsA = smem + wave * 4096;              // wave-uniform base; HW adds lane*16
    char* ldsB = smem + 16384 + wave * 4096;

    // 32x32x16 fragment coords: A[m = lane&31][k = (lane>>5)*8 + j]
    int m32 = lane & 31;
    int q2 = lane >> 5;                           // 0/1
    int m7 = m32 & 7;

    floatx16 acc[2][2];
#pragma unroll
    for (int i = 0; i < 2; ++i)
#pragma unroll
        for (int j = 0; j < 2; ++j) acc[i][j] = (floatx16)(0.0f);

#pragma unroll
    for (int kt = 0; kt < KK / BK; ++kt) {
        const int k0 = kt * BK;                   // compile-time; 128B steps
        async_copy16(aP0 + k0, ldsA);
        async_copy16(aP1 + k0, ldsA + 1024);
        async_copy16(aP2 + k0, ldsA + 2048);
        async_copy16(aP3 + k0, ldsA + 3072);
        async_copy16(bP0 + k0, ldsB);
        async_copy16(bP1 + k0, ldsB + 1024);
        async_copy16(bP2 + k0, ldsB + 2048);
        async_copy16(bP3 + k0, ldsB + 3072);
        __syncthreads();

#pragma unroll
        for (int ks = 0; ks < 4; ++ks) {          // 4 k-steps of 16
            int sl = ((ks * 2 + q2) ^ m7) * 8;    // swizzled element offset in row
            bf16x8 af[2], bfr[2];
#pragma unroll
            for (int mi = 0; mi < 2; ++mi)
                af[mi] = *(const bf16x8*)(As + (wm * 64 + mi * 32 + m32) * 64 + sl);
#pragma unroll
            for (int ni = 0; ni < 2; ++ni)
                bfr[ni] = *(const bf16x8*)(Bs + (wn * 64 + ni * 32 + m32) * 64 + sl);
#pragma unroll
            for (int mi = 0; mi < 2; ++mi)
#pragma unroll
                for (int ni = 0; ni < 2; ++ni)
                    acc[mi][ni] = __builtin_amdgcn_mfma_f32_32x32x16_bf16(
                        af[mi], bfr[ni], acc[mi][ni], 0, 0, 0);
        }
        __syncthreads();
    }

    // -------- fused epilogue (block-level, coalesced) --------
    // 32x32 C/D layout: col = lane&31, row = (reg&3) + 8*(reg>>2) + 4*(lane>>5).
    // Per mi round (2 rounds): waves dump acc[mi][*] into zs[64 rows][132]:
    //   zs row = wm*32 + inner_row, col = wn*64 + ni*32 + (lane&31)  (= u_b*4+g).
    // Then 256 threads process (row, u_b = tid&31) pairs: fully coalesced
    // c_in loads / out stores (128B per half-wave).
    float* zs = (float*)smem;                     // 64*132*4 = 33792 B
    int u_b = tid & 31;
    int u_glob = by * 32 + u_b;
    float vVi = Vi[u_glob], vVf = Vf[u_glob], vVo = Vo[u_glob];
    float vbi = bi_p[u_glob], vbf = bf_p[u_glob], vbc = bc_p[u_glob], vbo = bo_p[u_glob];

#pragma unroll
    for (int mi = 0; mi < 2; ++mi) {
        if (mi) __syncthreads();
#pragma unroll
        for (int ni = 0; ni < 2; ++ni)
#pragma unroll
            for (int reg = 0; reg < 16; ++reg) {
                int r = (reg & 3) + 8 * (reg >> 2) + 4 * q2;
                zs[(wm * 32 + r) * 132 + wn * 64 + ni * 32 + m32] = acc[mi][ni][reg];
            }
        __syncthreads();
#pragma unroll
        for (int t = 0; t < 8; ++t) {
            int rL = (tid >> 5) + t * 8;          // 0..63
            floatx4 z4 = *(const floatx4*)(zs + rL * 132 + u_b * 4);
            long row_glob = rm0 + (rL >> 5) * 64 + mi * 32 + (rL & 31);
            float cv = c_in[row_glob * 1024 + u_glob];
            float i_t = fast_sigmoid(z4[0] + vbi + vVi * cv);
            float f_t = fast_sigmoid(z4[1] + vbf + vVf * cv);
            float ctl = fast_tanh(z4[2] + vbc);
            float c_t = f_t * cv + i_t * ctl;
            float o_t = fast_sigmoid(z4[3] + vbo + vVo * c_t);
            float h_t = o_t * fast_tanh(c_t);
            out[row_glob * 1024 + u_glob] = h_t;
            out[8388608 + row_glob * 1024 + u_glob] = c_t;
        }
    }
}

extern "C" void kernel_launch(void* const* d_in, const int* in_sizes, int n_in,
                              void* d_out, int out_size, void* d_ws, size_t ws_size,
                              hipStream_t stream) {
    const float* x  = (const float*)d_in[0];
    const float* h  = (const float*)d_in[1];
    const float* c  = (const float*)d_in[2];
    const float* Wi = (const float*)d_in[3];
    const float* Wf = (const float*)d_in[4];
    const float* Wc = (const float*)d_in[5];
    const float* Wo = (const float*)d_in[6];
    const float* Ui = (const float*)d_in[7];
    const float* Uf = (const float*)d_in[8];
    const float* Uc = (const float*)d_in[9];
    const float* Uo = (const float*)d_in[10];
    const float* Vi = (const float*)d_in[11];
    const float* Vf = (const float*)d_in[12];
    const float* Vo = (const float*)d_in[13];
    const float* bi = (const float*)d_in[14];
    const float* bf = (const float*)d_in[15];
    const float* bc = (const float*)d_in[16];
    const float* bo = (const float*)d_in[17];

    unsigned short* Abf = (unsigned short*)d_ws;                          // 32 MB
    unsigned short* Wt  = (unsigned short*)((char*)d_ws + 33554432);      // 16 MB

    pack_all<<<dim3(10240), 256, 0, stream>>>(x, h, Wi, Wf, Wc, Wo,
                                              Ui, Uf, Uc, Uo, Abf, Wt);
    lstm_gemm<<<dim3(2048), 256, 0, stream>>>(Abf, Wt, c, Vi, Vf, Vo,
                                              bi, bf, bc, bo, (float*)d_out);
}